// Round 11
// baseline (596.239 us; speedup 1.0000x reference)
//
#include <hip/hip_runtime.h>
#include <hip/hip_bf16.h>
#include <hip/hip_cooperative_groups.h>

namespace cg = cooperative_groups;

// GCN forward, CSR-gather + split-bf16 MFMA, bf16 intermediates, fused build:
//   k_build (cooperative, 1 dispatch): xb=bf16(x); W splits; deg; CSR; dinv; goff; zero out
//   yb = bf16(dinv .* (xb @ W1))    A single-bf16, B split (k_gemm1_mfma)
//   h[v] = relu(dinv[v]*(yb[v] + sum_in yb[u]) + b1)  column-split 2-phase gather
//   zb = bf16(dinv .* (h @ W2))     h split in LDS, B split (k_gemm2_fused_mfma)
//   out[g] = mean_{v in g} dinv[v]*(zb[v] + sum_in zb[u]) + b2  (k_aggpool + k_final)

typedef __attribute__((ext_vector_type(8))) short short8;
typedef __attribute__((ext_vector_type(4))) float f32x4;

__device__ __forceinline__ void atomAddF(float* p, float v) { unsafeAtomicAdd(p, v); }

__device__ __forceinline__ unsigned short bf_rne(float f) {
  unsigned int u = __float_as_uint(f);
  return (unsigned short)((u + 0x7fffu + ((u >> 16) & 1u)) >> 16);
}
__device__ __forceinline__ float bf2f(unsigned short h) {
  return __uint_as_float(((unsigned int)h) << 16);
}
__device__ __forceinline__ float bf_lo(unsigned int u) { return __uint_as_float(u << 16); }
__device__ __forceinline__ float bf_hi(unsigned int u) { return __uint_as_float(u & 0xffff0000u); }

// ---------- cooperative build kernel: prep + CSR + dinv + goff + zero out ----------
__global__ void k_build(
    const float* __restrict__ x, const float* __restrict__ W1, const float* __restrict__ W2,
    const int* __restrict__ rows, const int* __restrict__ cols, const int* __restrict__ batch,
    unsigned short* __restrict__ xb,
    unsigned short* __restrict__ W1th, unsigned short* __restrict__ W1tl,
    unsigned short* __restrict__ W2th, unsigned short* __restrict__ W2tl,
    int* __restrict__ deg, int* __restrict__ off, int* __restrict__ partial,
    int* __restrict__ goff, int* __restrict__ csrsrc,
    float* __restrict__ dinv, float* __restrict__ out,
    int N, int E, int G)
{
  cg::grid_group grid = cg::this_grid();
  const int tid = threadIdx.x;
  const int gtid = blockIdx.x * 256 + tid;
  const int nthr = gridDim.x * 256;
  const int nch = (N + 255) >> 8;          // 391 chunks of 256
  __shared__ int sh[256];
  __shared__ int sp[512];

  // ---- phase A: prepx, prepw, zero deg, zero out ----
  {
    long total8 = (long)N * 16;
    for (long i = gtid; i < total8; i += nthr) {
      const float4* in = (const float4*)(x + i * 8);
      float4 a = in[0], b = in[1];
      short8 o;
      o[0] = (short)bf_rne(a.x); o[1] = (short)bf_rne(a.y);
      o[2] = (short)bf_rne(a.z); o[3] = (short)bf_rne(a.w);
      o[4] = (short)bf_rne(b.x); o[5] = (short)bf_rne(b.y);
      o[6] = (short)bf_rne(b.z); o[7] = (short)bf_rne(b.w);
      *(short8*)(xb + i * 8) = o;
    }
    for (int i = gtid; i < 16384 + 8192; i += nthr) {
      if (i < 16384) {
        int c = i >> 7, k = i & 127;
        float f = W1[k * 128 + c];
        unsigned short hi = bf_rne(f);
        W1th[i] = hi; W1tl[i] = bf_rne(f - bf2f(hi));
      } else {
        int j = i - 16384;
        int c = j >> 7, k = j & 127;
        float f = W2[k * 64 + c];
        unsigned short hi = bf_rne(f);
        W2th[j] = hi; W2tl[j] = bf_rne(f - bf2f(hi));
      }
    }
    for (int i = gtid; i < N; i += nthr) deg[i] = 0;
    for (int i = gtid; i < G * 64; i += nthr) out[i] = 0.f;
  }
  grid.sync();

  // ---- phase B: in-degree count ----
  for (int e = gtid; e < E; e += nthr) atomicAdd(&deg[cols[e]], 1);
  grid.sync();

  // ---- phase C: per-chunk block sums ----
  for (int c = blockIdx.x; c < nch; c += gridDim.x) {
    int i = c * 256 + tid;
    sh[tid] = (i < N) ? deg[i] : 0;
    __syncthreads();
    for (int o = 128; o > 0; o >>= 1) {
      if (tid < o) sh[tid] += sh[tid + o];
      __syncthreads();
    }
    if (tid == 0) partial[c] = sh[0];
    __syncthreads();
  }
  grid.sync();

  // ---- phase D: exclusive scan of partial (block 0, serial in LDS) ----
  if (blockIdx.x == 0) {
    for (int i = tid; i < 512; i += 256) sp[i] = (i < nch) ? partial[i] : 0;
    __syncthreads();
    if (tid == 0) {
      int run = 0;
      for (int i = 0; i < nch; ++i) { int v = sp[i]; sp[i] = run; run += v; }
    }
    __syncthreads();
    for (int i = tid; i < nch; i += 256) partial[i] = sp[i];
  }
  grid.sync();

  // ---- phase E: per-chunk exclusive scan -> off, cursor(deg), dinv ----
  for (int c = blockIdx.x; c < nch; c += gridDim.x) {
    int i = c * 256 + tid;
    int v = (i < N) ? deg[i] : 0;
    sh[tid] = v;
    __syncthreads();
    for (int o = 1; o < 256; o <<= 1) {
      int xval = (tid >= o) ? sh[tid - o] : 0;
      __syncthreads();
      sh[tid] += xval;
      __syncthreads();
    }
    if (i < N) {
      int excl = partial[c] + sh[tid] - v;
      off[i] = excl;
      deg[i] = excl;                       // fill cursor
      dinv[i] = rsqrtf((float)v + 1.0f);   // +1 self-loop
      if (i == N - 1) off[N] = excl + v;
    }
    __syncthreads();
  }
  grid.sync();

  // ---- phase F: fill CSR + goff ----
  for (int e = gtid; e < E; e += nthr) {
    int pos = atomicAdd(&deg[cols[e]], 1);
    csrsrc[pos] = rows[e];
  }
  for (int g = gtid; g <= G; g += nthr) {
    int lo = 0, hi = N;
    while (lo < hi) {
      int m = (lo + hi) >> 1;
      if (batch[m] < g) lo = m + 1; else hi = m;
    }
    goff[g] = lo;
  }
}

// ---------- GEMM1: yb = bf16(dinv .* (xb @ W1)); A single, B split ----------
__global__ __launch_bounds__(256) void k_gemm1_mfma(
    const unsigned short* __restrict__ xb,
    const unsigned short* __restrict__ W1th, const unsigned short* __restrict__ W1tl,
    const float* __restrict__ dinv, unsigned short* __restrict__ yb, int N)
{
  const int tid = threadIdx.x;
  const int w = tid >> 6, l = tid & 63;
  const int v0 = blockIdx.x * 64;
  const int l15 = l & 15, lh = l >> 4;

  short8 bh[2][4], bl[2][4];
#pragma unroll
  for (int ct = 0; ct < 2; ++ct) {
    int colr = 32 * w + 16 * ct + l15;
#pragma unroll
    for (int ks = 0; ks < 4; ++ks) {
      bh[ct][ks] = *(const short8*)(W1th + colr * 128 + ks * 32 + 8 * lh);
      bl[ct][ks] = *(const short8*)(W1tl + colr * 128 + ks * 32 + 8 * lh);
    }
  }

  short8 af0_0, af0_1, af0_2, af0_3;
  short8 af1_0, af1_1, af1_2, af1_3;
  short8 af2_0, af2_1, af2_2, af2_3;
  short8 af3_0, af3_1, af3_2, af3_3;
  {
    int r0 = v0 + 0 * 16 + l15; if (r0 >= N) r0 = N - 1;
    int r1 = v0 + 1 * 16 + l15; if (r1 >= N) r1 = N - 1;
    int r2 = v0 + 2 * 16 + l15; if (r2 >= N) r2 = N - 1;
    int r3 = v0 + 3 * 16 + l15; if (r3 >= N) r3 = N - 1;
    const unsigned short* a0 = xb + (size_t)r0 * 128 + 8 * lh;
    const unsigned short* a1 = xb + (size_t)r1 * 128 + 8 * lh;
    const unsigned short* a2 = xb + (size_t)r2 * 128 + 8 * lh;
    const unsigned short* a3 = xb + (size_t)r3 * 128 + 8 * lh;
    af0_0 = *(const short8*)(a0);      af0_1 = *(const short8*)(a0 + 32);
    af0_2 = *(const short8*)(a0 + 64); af0_3 = *(const short8*)(a0 + 96);
    af1_0 = *(const short8*)(a1);      af1_1 = *(const short8*)(a1 + 32);
    af1_2 = *(const short8*)(a1 + 64); af1_3 = *(const short8*)(a1 + 96);
    af2_0 = *(const short8*)(a2);      af2_1 = *(const short8*)(a2 + 32);
    af2_2 = *(const short8*)(a2 + 64); af2_3 = *(const short8*)(a2 + 96);
    af3_0 = *(const short8*)(a3);      af3_1 = *(const short8*)(a3 + 32);
    af3_2 = *(const short8*)(a3 + 64); af3_3 = *(const short8*)(a3 + 96);
  }

#pragma unroll
  for (int rt = 0; rt < 4; ++rt) {
    short8 k0 = (rt == 0) ? af0_0 : (rt == 1) ? af1_0 : (rt == 2) ? af2_0 : af3_0;
    short8 k1 = (rt == 0) ? af0_1 : (rt == 1) ? af1_1 : (rt == 2) ? af2_1 : af3_1;
    short8 k2 = (rt == 0) ? af0_2 : (rt == 1) ? af1_2 : (rt == 2) ? af2_2 : af3_2;
    short8 k3 = (rt == 0) ? af0_3 : (rt == 1) ? af1_3 : (rt == 2) ? af2_3 : af3_3;
    f32x4 acc0 = {0.f, 0.f, 0.f, 0.f}, acc1 = {0.f, 0.f, 0.f, 0.f};
    acc0 = __builtin_amdgcn_mfma_f32_16x16x32_bf16(k0, bh[0][0], acc0, 0, 0, 0);
    acc1 = __builtin_amdgcn_mfma_f32_16x16x32_bf16(k0, bh[1][0], acc1, 0, 0, 0);
    acc0 = __builtin_amdgcn_mfma_f32_16x16x32_bf16(k0, bl[0][0], acc0, 0, 0, 0);
    acc1 = __builtin_amdgcn_mfma_f32_16x16x32_bf16(k0, bl[1][0], acc1, 0, 0, 0);
    acc0 = __builtin_amdgcn_mfma_f32_16x16x32_bf16(k1, bh[0][1], acc0, 0, 0, 0);
    acc1 = __builtin_amdgcn_mfma_f32_16x16x32_bf16(k1, bh[1][1], acc1, 0, 0, 0);
    acc0 = __builtin_amdgcn_mfma_f32_16x16x32_bf16(k1, bl[0][1], acc0, 0, 0, 0);
    acc1 = __builtin_amdgcn_mfma_f32_16x16x32_bf16(k1, bl[1][1], acc1, 0, 0, 0);
    acc0 = __builtin_amdgcn_mfma_f32_16x16x32_bf16(k2, bh[0][2], acc0, 0, 0, 0);
    acc1 = __builtin_amdgcn_mfma_f32_16x16x32_bf16(k2, bh[1][2], acc1, 0, 0, 0);
    acc0 = __builtin_amdgcn_mfma_f32_16x16x32_bf16(k2, bl[0][2], acc0, 0, 0, 0);
    acc1 = __builtin_amdgcn_mfma_f32_16x16x32_bf16(k2, bl[1][2], acc1, 0, 0, 0);
    acc0 = __builtin_amdgcn_mfma_f32_16x16x32_bf16(k3, bh[0][3], acc0, 0, 0, 0);
    acc1 = __builtin_amdgcn_mfma_f32_16x16x32_bf16(k3, bh[1][3], acc1, 0, 0, 0);
    acc0 = __builtin_amdgcn_mfma_f32_16x16x32_bf16(k3, bl[0][3], acc0, 0, 0, 0);
    acc1 = __builtin_amdgcn_mfma_f32_16x16x32_bf16(k3, bl[1][3], acc1, 0, 0, 0);

    int r4 = v0 + rt * 16 + lh * 4;
    float4 d4 = *(const float4*)(dinv + r4);   // overread guarded by store condition
    int col0 = 32 * w + l15;
#pragma unroll
    for (int reg = 0; reg < 4; ++reg) {
      int row = r4 + reg;
      if (row < N) {
        float dd = (reg == 0) ? d4.x : (reg == 1) ? d4.y : (reg == 2) ? d4.z : d4.w;
        yb[(size_t)row * 128 + col0]      = bf_rne(acc0[reg] * dd);
        yb[(size_t)row * 128 + col0 + 16] = bf_rne(acc1[reg] * dd);
      }
    }
  }
}

// ---------- GEMM2 fused with layer-1 aggregation ----------
// Column-split gather: phase ph gathers dims [64ph, 64ph+64) only -> active yb
// working set halves (L2 locality). 8 threads/node x 8 dims/phase, MLP-8.
// Swizzle: byte = (vn*256 + dim*2) ^ ((vn&7)<<4), composed BEFORE the XOR.
__global__ __launch_bounds__(256, 4) void k_gemm2_fused_mfma(
    const unsigned short* __restrict__ yb, const int* __restrict__ off,
    const int* __restrict__ src,
    const unsigned short* __restrict__ W2th, const unsigned short* __restrict__ W2tl,
    const float* __restrict__ dinv, const float* __restrict__ b1,
    unsigned short* __restrict__ zb, int N)
{
  __shared__ __align__(16) unsigned short hh[32 * 128];   // 8 KB
  __shared__ __align__(16) unsigned short hl[32 * 128];   // 8 KB
  const int tid = threadIdx.x;
  const int w = tid >> 6, l = tid & 63;
  const int v0 = blockIdx.x * 32;
  const int l15 = l & 15, lh = l >> 4;

  { // gather: 8 threads/node, 2 column phases of 8 dims each, MLP-8
    int vn = tid >> 3;                 // 0..31
    int d8 = (tid & 7) << 3;           // 0..56
    int vv = v0 + vn;
    int vc = (vv < N) ? vv : N - 1;
    int e0 = off[vc], e1 = off[vc + 1];
    int last = e1 - 1;
    float d = dinv[vc];
#pragma unroll
    for (int ph = 0; ph < 2; ++ph) {
      int cd = ph * 64 + d8;           // dim base for this phase
      float acc[8];
      { // self row (16 B)
        uint4 t = *(const uint4*)(yb + (size_t)vc * 128 + cd);
        acc[0] = bf_lo(t.x); acc[1] = bf_hi(t.x);
        acc[2] = bf_lo(t.y); acc[3] = bf_hi(t.y);
        acc[4] = bf_lo(t.z); acc[5] = bf_hi(t.z);
        acc[6] = bf_lo(t.w); acc[7] = bf_hi(t.w);
      }
      for (int i = e0; i < e1; i += 8) {
        int i1 = i + 1, i2 = i + 2, i3 = i + 3, i4 = i + 4, i5 = i + 5, i6 = i + 6, i7 = i + 7;
        int u0 = src[i];
        int u1 = src[i1 <= last ? i1 : last];
        int u2 = src[i2 <= last ? i2 : last];
        int u3 = src[i3 <= last ? i3 : last];
        int u4 = src[i4 <= last ? i4 : last];
        int u5 = src[i5 <= last ? i5 : last];
        int u6 = src[i6 <= last ? i6 : last];
        int u7 = src[i7 <= last ? i7 : last];
        float m1 = (i1 <= last) ? 1.f : 0.f;
        float m2 = (i2 <= last) ? 1.f : 0.f;
        float m3 = (i3 <= last) ? 1.f : 0.f;
        float m4 = (i4 <= last) ? 1.f : 0.f;
        float m5 = (i5 <= last) ? 1.f : 0.f;
        float m6 = (i6 <= last) ? 1.f : 0.f;
        float m7 = (i7 <= last) ? 1.f : 0.f;
        uint4 t0 = *(const uint4*)(yb + (size_t)u0 * 128 + cd);
        uint4 t1 = *(const uint4*)(yb + (size_t)u1 * 128 + cd);
        uint4 t2 = *(const uint4*)(yb + (size_t)u2 * 128 + cd);
        uint4 t3 = *(const uint4*)(yb + (size_t)u3 * 128 + cd);
        uint4 t4 = *(const uint4*)(yb + (size_t)u4 * 128 + cd);
        uint4 t5 = *(const uint4*)(yb + (size_t)u5 * 128 + cd);
        uint4 t6 = *(const uint4*)(yb + (size_t)u6 * 128 + cd);
        uint4 t7 = *(const uint4*)(yb + (size_t)u7 * 128 + cd);
        acc[0] += bf_lo(t0.x) + m1*bf_lo(t1.x) + m2*bf_lo(t2.x) + m3*bf_lo(t3.x)
                + m4*bf_lo(t4.x) + m5*bf_lo(t5.x) + m6*bf_lo(t6.x) + m7*bf_lo(t7.x);
        acc[1] += bf_hi(t0.x) + m1*bf_hi(t1.x) + m2*bf_hi(t2.x) + m3*bf_hi(t3.x)
                + m4*bf_hi(t4.x) + m5*bf_hi(t5.x) + m6*bf_hi(t6.x) + m7*bf_hi(t7.x);
        acc[2] += bf_lo(t0.y) + m1*bf_lo(t1.y) + m2*bf_lo(t2.y) + m3*bf_lo(t3.y)
                + m4*bf_lo(t4.y) + m5*bf_lo(t5.y) + m6*bf_lo(t6.y) + m7*bf_lo(t7.y);
        acc[3] += bf_hi(t0.y) + m1*bf_hi(t1.y) + m2*bf_hi(t2.y) + m3*bf_hi(t3.y)
                + m4*bf_hi(t4.y) + m5*bf_hi(t5.y) + m6*bf_hi(t6.y) + m7*bf_hi(t7.y);
        acc[4] += bf_lo(t0.z) + m1*bf_lo(t1.z) + m2*bf_lo(t2.z) + m3*bf_lo(t3.z)
                + m4*bf_lo(t4.z) + m5*bf_lo(t5.z) + m6*bf_lo(t6.z) + m7*bf_lo(t7.z);
        acc[5] += bf_hi(t0.z) + m1*bf_hi(t1.z) + m2*bf_hi(t2.z) + m3*bf_hi(t3.z)
                + m4*bf_hi(t4.z) + m5*bf_hi(t5.z) + m6*bf_hi(t6.z) + m7*bf_hi(t7.z);
        acc[6] += bf_lo(t0.w) + m1*bf_lo(t1.w) + m2*bf_lo(t2.w) + m3*bf_lo(t3.w)
                + m4*bf_lo(t4.w) + m5*bf_lo(t5.w) + m6*bf_lo(t6.w) + m7*bf_lo(t7.w);
        acc[7] += bf_hi(t0.w) + m1*bf_hi(t1.w) + m2*bf_hi(t2.w) + m3*bf_hi(t3.w)
                + m4*bf_hi(t4.w) + m5*bf_hi(t5.w) + m6*bf_hi(t6.w) + m7*bf_hi(t7.w);
      }
      // h = relu(d*acc + b1) -> split bf16 -> swizzled LDS
      short8 oh, ol;
#pragma unroll
      for (int j = 0; j < 8; ++j) {
        float hv = fmaxf(fmaf(d, acc[j], b1[cd + j]), 0.f);
        unsigned short hb = bf_rne(hv);
        oh[j] = (short)hb;
        ol[j] = (short)bf_rne(hv - bf2f(hb));
      }
      int byte = (vn * 256 + cd * 2) ^ ((vn & 7) << 4);
      *(short8*)((char*)hh + byte) = oh;
      *(short8*)((char*)hl + byte) = ol;
    }
  }

  // W2 B-frags hi/lo
  short8 bh[4], bl[4];
  {
    int colr = 16 * w + l15;
#pragma unroll
    for (int ks = 0; ks < 4; ++ks) {
      bh[ks] = *(const short8*)(W2th + colr * 128 + ks * 32 + 8 * lh);
      bl[ks] = *(const short8*)(W2tl + colr * 128 + ks * 32 + 8 * lh);
    }
  }
  __syncthreads();

  // MFMA phase: 2 row-tiles x 12 MFMAs
#pragma unroll
  for (int rt = 0; rt < 2; ++rt) {
    int row = rt * 16 + l15;
    const int swz = (row & 7) << 4;
    const int base = row * 256 + lh * 16;
    f32x4 acc = {0.f, 0.f, 0.f, 0.f};
#pragma unroll
    for (int ks = 0; ks < 4; ++ks) {
      int byte = (base + ks * 64) ^ swz;      // compose THEN xor
      short8 ah = *(const short8*)((char*)hh + byte);
      short8 al = *(const short8*)((char*)hl + byte);
      acc = __builtin_amdgcn_mfma_f32_16x16x32_bf16(ah, bh[ks], acc, 0, 0, 0);
      acc = __builtin_amdgcn_mfma_f32_16x16x32_bf16(al, bh[ks], acc, 0, 0, 0);
      acc = __builtin_amdgcn_mfma_f32_16x16x32_bf16(ah, bl[ks], acc, 0, 0, 0);
    }

    int r4 = v0 + rt * 16 + lh * 4;
    float4 d4 = *(const float4*)(dinv + r4);
    int col = 16 * w + l15;
#pragma unroll
    for (int reg = 0; reg < 4; ++reg) {
      int rr = r4 + reg;
      if (rr < N) {
        float dd = (reg == 0) ? d4.x : (reg == 1) ? d4.y : (reg == 2) ? d4.z : d4.w;
        zb[(size_t)rr * 64 + col] = bf_rne(acc[reg] * dd);
      }
    }
  }
}

// ---------- layer-2 aggregation + pool (gather, bf16 z) ----------
__global__ __launch_bounds__(256) void k_aggpool(
    const unsigned short* __restrict__ zb, const int* __restrict__ off,
    const int* __restrict__ src, const float* __restrict__ dinv,
    const int* __restrict__ goff, float* __restrict__ out, int N)
{
  int g = blockIdx.x >> 3, seg = blockIdx.x & 7;
  int w = threadIdx.x >> 6, lane = threadIdx.x & 63;
  int lo = goff[g], hi = goff[g + 1];
  float acc = 0.f;
  for (int v = lo + seg * 4 + w; v < hi; v += 32) {
    float sv = bf2f(zb[(size_t)v * 64 + lane]);
    int e0 = off[v], e1 = off[v + 1];
    int last = e1 - 1;
    for (int i = e0; i < e1; i += 4) {
      int i1 = i + 1, i2 = i + 2, i3 = i + 3;
      int u0 = src[i];
      int u1 = src[i1 <= last ? i1 : last];
      int u2 = src[i2 <= last ? i2 : last];
      int u3 = src[i3 <= last ? i3 : last];
      float a0 = bf2f(zb[(size_t)u0 * 64 + lane]);
      float a1 = bf2f(zb[(size_t)u1 * 64 + lane]);
      float a2 = bf2f(zb[(size_t)u2 * 64 + lane]);
      float a3 = bf2f(zb[(size_t)u3 * 64 + lane]);
      sv += a0;
      sv += (i1 <= last) ? a1 : 0.f;
      sv += (i2 <= last) ? a2 : 0.f;
      sv += (i3 <= last) ? a3 : 0.f;
    }
    acc = fmaf(dinv[v], sv, acc);
  }
  atomAddF(out + (size_t)g * 64 + lane, acc);
}

__global__ __launch_bounds__(256) void k_final(float* __restrict__ out,
    const int* __restrict__ goff, const float* __restrict__ b2, int total) {
  int i = blockIdx.x * 256 + threadIdx.x;
  if (i >= total) return;
  int g = i >> 6, d = i & 63;
  int n = goff[g + 1] - goff[g];
  out[i] = (n > 0) ? out[i] / (float)n + b2[d] : 0.f;
}

extern "C" void kernel_launch(void* const* d_in, const int* in_sizes, int n_in,
                              void* d_out, int out_size, void* d_ws, size_t ws_size,
                              hipStream_t stream) {
  const float* x     = (const float*)d_in[0];
  const int*   eidx  = (const int*)d_in[1];
  const int*   batch = (const int*)d_in[2];
  const float* W1    = (const float*)d_in[3];
  const float* b1    = (const float*)d_in[4];
  const float* W2    = (const float*)d_in[5];
  const float* b2    = (const float*)d_in[6];
  float* out = (float*)d_out;

  const int N = in_sizes[2];          // 100000
  const int E = in_sizes[1] / 2;      // 640000
  const int G = out_size / 64;        // 256

  const int* rows = eidx;             // sources
  const int* cols = eidx + E;         // targets

  // workspace (elements):
  // [xb N*128 u16][yb N*128 u16][zb N*64 u16][W1th 16384][W1tl 16384][W2th 8192][W2tl 8192]
  // [dinv N f][deg N i][off N+1 i][partial 512 i][goff G+1 i][csrsrc E i]
  unsigned short* xb  = (unsigned short*)d_ws;
  unsigned short* yb  = xb + (size_t)N * 128;
  unsigned short* zb  = yb + (size_t)N * 128;
  unsigned short* W1th = zb + (size_t)N * 64;
  unsigned short* W1tl = W1th + 16384;
  unsigned short* W2th = W1tl + 16384;
  unsigned short* W2tl = W2th + 8192;
  float* dinv    = (float*)(W2tl + 8192);
  int*   deg     = (int*)(dinv + N);
  int*   off     = deg + N;
  int*   partial = off + N + 1;
  int*   goff    = partial + 512;
  int*   csrsrc  = goff + G + 1;

  const int B = 256;

  // single cooperative build dispatch (replaces 10 dispatches incl. memsets)
  {
    void* kb_x = (void*)x; void* kb_W1 = (void*)W1; void* kb_W2 = (void*)W2;
    void* kb_rows = (void*)rows; void* kb_cols = (void*)cols; void* kb_batch = (void*)batch;
    void* kb_xb = (void*)xb;
    void* kb_W1th = (void*)W1th; void* kb_W1tl = (void*)W1tl;
    void* kb_W2th = (void*)W2th; void* kb_W2tl = (void*)W2tl;
    void* kb_deg = (void*)deg; void* kb_off = (void*)off; void* kb_partial = (void*)partial;
    void* kb_goff = (void*)goff; void* kb_csrsrc = (void*)csrsrc;
    void* kb_dinv = (void*)dinv; void* kb_out = (void*)out;
    int nN = N, nE = E, nG = G;
    void* args[] = { &kb_x, &kb_W1, &kb_W2, &kb_rows, &kb_cols, &kb_batch,
                     &kb_xb, &kb_W1th, &kb_W1tl, &kb_W2th, &kb_W2tl,
                     &kb_deg, &kb_off, &kb_partial, &kb_goff, &kb_csrsrc,
                     &kb_dinv, &kb_out, &nN, &nE, &nG };
    hipLaunchCooperativeKernel((const void*)k_build, dim3(512), dim3(B), args, 0, stream);
  }

  // layer 1 transform (A single-bf16, B split)
  k_gemm1_mfma<<<(N + 63) / 64, B, 0, stream>>>(xb, W1th, W1tl, dinv, yb, N);
  // layer 1 aggregate + relu + layer 2 transform (column-split gather + split MFMA)
  k_gemm2_fused_mfma<<<(N + 31) / 32, B, 0, stream>>>(yb, off, csrsrc, W2th, W2tl, dinv, b1, zb, N);
  // layer 2 aggregate + pool + finalize
  k_aggpool<<<G * 8, B, 0, stream>>>(zb, off, csrsrc, dinv, goff, out, N);
  k_final<<<(out_size + B - 1) / B, B, 0, stream>>>(out, goff, b2, out_size);
}